// Round 1
// baseline (722.834 us; speedup 1.0000x reference)
//
#include <hip/hip_runtime.h>

typedef _Float16 f16;
typedef _Float16 f16x8 __attribute__((ext_vector_type(8)));
typedef _Float16 f16x4 __attribute__((ext_vector_type(4)));
typedef float    f32x4 __attribute__((ext_vector_type(4)));

#define NB 4
#define SEQ 4096
#define DIM 512
#define MTOT (NB*SEQ)   // 16384
#define NEL ((size_t)MTOT*DIM)

// ---------------------------------------------------------------------------
// Projection GEMM: out[m,n] = f16( sum_k A[m,k] * W[n,k] + bias[n] )
// p: 0:q natural  1:qv natural  2:k K-swizzled  3:kv V-swizzled
// Swizzled layouts (per batch, per 32-row kv tile t, per 256-D chunk), unit=8 f16:
//  K: unit = t*2048 + chunk*1024 + n*32 + ((ksl*4+q+n)&31), elem j
//     where d = chunk*256 + ksl*32 + q*8 + j, n = s&31
//  V: unit = t*2048 + chunk*1024 + dl*4 + ((q+(dl>>1))&3), elem j
//     where s = t*32 + q*8 + j, dl = d&255
// ---------------------------------------------------------------------------
__global__ __launch_bounds__(256) void proj_gemm(
    const float* __restrict__ x, const float* __restrict__ y,
    const float* __restrict__ Wq, const float* __restrict__ bq,
    const float* __restrict__ Wqv, const float* __restrict__ bqv,
    const float* __restrict__ Wk, const float* __restrict__ bk,
    const float* __restrict__ Wkv, const float* __restrict__ bkv,
    f16* __restrict__ qh, f16* __restrict__ qvh,
    f16* __restrict__ kS, f16* __restrict__ vS)
{
    __shared__ __attribute__((aligned(16))) f16 a_lds[128][40];
    __shared__ __attribute__((aligned(16))) f16 b_lds[128][40];

    const int p = blockIdx.z;
    const float* A    = (p < 2) ? x : y;
    const float* W    = (p==0)?Wq:(p==1)?Wqv:(p==2)?Wk:Wkv;
    const float* bias = (p==0)?bq:(p==1)?bqv:(p==2)?bk:bkv;

    const int m0 = blockIdx.y * 128, n0 = blockIdx.x * 128;
    const int tid = threadIdx.x, lane = tid & 63, wv = tid >> 6;
    const int wm = wv >> 1, wn = wv & 1, mrow = lane & 15, qd = lane >> 4;

    f32x4 acc[4][4];
#pragma unroll
    for (int mt = 0; mt < 4; ++mt)
#pragma unroll
        for (int nt = 0; nt < 4; ++nt) acc[mt][nt] = (f32x4){0.f,0.f,0.f,0.f};

    float bv[4];
#pragma unroll
    for (int nt = 0; nt < 4; ++nt) bv[nt] = bias[n0 + wn*64 + nt*16 + mrow];

    for (int k0 = 0; k0 < DIM; k0 += 32) {
        __syncthreads();
#pragma unroll
        for (int i = 0; i < 4; ++i) {
            int c = i*256 + tid;
            int row = c >> 3, c4 = c & 7;
            float4 v = *(const float4*)(A + (size_t)(m0+row)*DIM + k0 + c4*4);
            f16x4 hh = { (f16)v.x, (f16)v.y, (f16)v.z, (f16)v.w };
            *(f16x4*)&a_lds[row][c4*4] = hh;
        }
#pragma unroll
        for (int i = 0; i < 4; ++i) {
            int c = i*256 + tid;
            int row = c >> 3, c4 = c & 7;
            float4 v = *(const float4*)(W + (size_t)(n0+row)*DIM + k0 + c4*4);
            f16x4 hh = { (f16)v.x, (f16)v.y, (f16)v.z, (f16)v.w };
            *(f16x4*)&b_lds[row][c4*4] = hh;
        }
        __syncthreads();
        f16x8 af[4], bfr[4];
#pragma unroll
        for (int mt = 0; mt < 4; ++mt) af[mt]  = *(const f16x8*)&a_lds[wm*64 + mt*16 + mrow][qd*8];
#pragma unroll
        for (int nt = 0; nt < 4; ++nt) bfr[nt] = *(const f16x8*)&b_lds[wn*64 + nt*16 + mrow][qd*8];
#pragma unroll
        for (int mt = 0; mt < 4; ++mt)
#pragma unroll
            for (int nt = 0; nt < 4; ++nt)
                acc[mt][nt] = __builtin_amdgcn_mfma_f32_16x16x32_f16(af[mt], bfr[nt], acc[mt][nt], 0,0,0);
    }

#pragma unroll
    for (int mt = 0; mt < 4; ++mt)
#pragma unroll
        for (int r = 0; r < 4; ++r) {
            int g = m0 + wm*64 + mt*16 + qd*4 + r;
#pragma unroll
            for (int nt = 0; nt < 4; ++nt) {
                int d = n0 + wn*64 + nt*16 + mrow;
                f16 val = (f16)(acc[mt][nt][r] + bv[nt]);
                if (p == 0) {
                    qh[(size_t)g*DIM + d] = val;
                } else if (p == 1) {
                    qvh[(size_t)g*DIM + d] = val;
                } else if (p == 2) {
                    int b = g >> 12, s = g & 4095;
                    int t = s >> 5, n = s & 31;
                    int chunk = d >> 8, ksl = (d >> 5) & 7, q = (d >> 3) & 3, j = d & 7;
                    size_t idx = (((size_t)((b*128 + t)*2048 + chunk*1024
                                   + n*32 + ((ksl*4 + q + n) & 31))) << 3) + j;
                    kS[idx] = val;
                } else {
                    int b = g >> 12, s = g & 4095;
                    int t = s >> 5, q = (s >> 3) & 3, j = s & 7;
                    int chunk = d >> 8, dl = d & 255;
                    size_t idx = (((size_t)((b*128 + t)*2048 + chunk*1024
                                   + dl*4 + ((q + (dl >> 1)) & 3))) << 3) + j;
                    vS[idx] = val;
                }
            }
        }
}

// ---------------------------------------------------------------------------
// global -> LDS direct DMA, 16B per lane. LDS dest must be wave-uniform base;
// HW adds lane*16. Global src is per-lane.
// ---------------------------------------------------------------------------
__device__ __forceinline__ void gl_lds16(const f16* g, f16* l)
{
    __builtin_amdgcn_global_load_lds(
        (const __attribute__((address_space(1))) void*)g,
        (__attribute__((address_space(3))) void*)l, 16, 0, 0);
}

// ---------------------------------------------------------------------------
// Flash attention v2: 256 blocks (1/CU), 512 threads / 8 waves -> 2 waves/SIMD.
// Wave pair (g, g+4) shares 16 Q rows; waves 0-3 sweep EVEN 32-row KV tiles,
// waves 4-7 sweep ODD tiles (parity-bound LDS slots -> loop-invariant read
// addresses). Online-softmax halves merged at end through the (dead) K/V LDS.
// Staging per iteration-pair: K register-staged (issued at compute top, stored
// after barrier A), V DMA'd via global_load_lds in the store interval (zero
// VGPR; latency hidden under the K stores; barrier B's vmcnt(0) drain = ready).
// ---------------------------------------------------------------------------
__global__ __launch_bounds__(512, 2) void attn_kernel(
    const f16* __restrict__ qh, const f16* __restrict__ kS,
    const f16* __restrict__ vS, const f16* __restrict__ qvh,
    f16* __restrict__ ao)
{
    __shared__ __attribute__((aligned(16))) f16 kbuf[2][16384];  // 2 x 32KB (parity)
    __shared__ __attribute__((aligned(16))) f16 vbuf[2][16384];  // 2 x 32KB (parity)
    __shared__ __attribute__((aligned(16))) f16 p_lds[8][16][40];
    __shared__ float mexch[8][4][4];
    __shared__ float lexch[8][4][4];

    const int xcd = blockIdx.x & 7;
    const int b   = xcd >> 1;                          // batch -> XCD pair
    const int qt  = (blockIdx.x >> 3) * 2 + (xcd & 1); // 0..63
    const int tid = threadIdx.x, lane = tid & 63, w = tid >> 6;
    const int g = w & 3, half = w >> 2;                // Q group / KV parity
    const int mrow = lane & 15, qd = lane >> 4;

    const f16* kSb = kS + ((size_t)b << 21);
    const f16* vSb = vS + ((size_t)b << 21);

    const f16* kb = &kbuf[half][0];
    const f16* vb = &vbuf[half][0];

    // Q fragments (A-layout): lane m+16q holds Q[m][32*ks + 8q + j]
    const size_t qrow = ((size_t)b*SEQ + qt*64 + g*16 + mrow) * DIM;
    f16x8 qf[16];
#pragma unroll
    for (int ks = 0; ks < 16; ++ks)
        qf[ks] = *(const f16x8*)(qh + qrow + ks*32 + qd*8);

    f32x4 o[32];
#pragma unroll
    for (int nt = 0; nt < 32; ++nt) o[nt] = (f32x4){0.f,0.f,0.f,0.f};
    f32x4 o_l = (f32x4){0.f,0.f,0.f,0.f};
    float m_i[4] = {-INFINITY,-INFINITY,-INFINITY,-INFINITY};
    const f16x8 ones = {(f16)1.f,(f16)1.f,(f16)1.f,(f16)1.f,
                        (f16)1.f,(f16)1.f,(f16)1.f,(f16)1.f};

    // prologue: DMA tiles 0 (slot 0) and 1 (slot 1), K and V
#pragma unroll
    for (int u = 0; u < 4; ++u) {
        const int ubase = (u*8 + w) * 64;              // wave-uniform unit base
        gl_lds16(kSb + (size_t)(ubase + lane)*8,          (f16*)&kbuf[0][ubase*8]);
        gl_lds16(kSb + (size_t)(2048 + ubase + lane)*8,   (f16*)&kbuf[1][ubase*8]);
        gl_lds16(vSb + (size_t)(ubase + lane)*8,          (f16*)&vbuf[0][ubase*8]);
        gl_lds16(vSb + (size_t)(2048 + ubase + lane)*8,   (f16*)&vbuf[1][ubase*8]);
    }
    __syncthreads();

    f16x8 skA[4], skB[4];
    for (int j = 0; j < 64; ++j) {
        // issue next K tile-pair loads NOW; consumed after barrier A
        if (j < 63) {
            const size_t t0 = (size_t)(2*j + 2) * 2048;
#pragma unroll
            for (int u = 0; u < 4; ++u) {
                const int unit = u*512 + tid;
                skA[u] = *(const f16x8*)(kSb + (t0 + unit)*8);
                skB[u] = *(const f16x8*)(kSb + (t0 + 2048 + unit)*8);
            }
        }

        // S = Q K^T : 16x32 per wave on tile (2j+half); 4 independent chains
        f32x4 s0a = (f32x4){0.f,0.f,0.f,0.f}, s0b = s0a, s1a = s0a, s1b = s0a;
#pragma unroll
        for (int ksl = 0; ksl < 8; ++ksl) {
            int n0a = mrow, n1a = 16 + mrow;
            f16x8 kf0 = *(const f16x8*)&kb[(n0a*32 + ((ksl*4 + qd + n0a) & 31)) << 3];
            f16x8 kf1 = *(const f16x8*)&kb[(n1a*32 + ((ksl*4 + qd + n1a) & 31)) << 3];
            f16x8 kg0 = *(const f16x8*)&kb[(1024 + n0a*32 + ((ksl*4 + qd + n0a) & 31)) << 3];
            f16x8 kg1 = *(const f16x8*)&kb[(1024 + n1a*32 + ((ksl*4 + qd + n1a) & 31)) << 3];
            s0a = __builtin_amdgcn_mfma_f32_16x16x32_f16(qf[ksl],     kf0, s0a, 0,0,0);
            s1a = __builtin_amdgcn_mfma_f32_16x16x32_f16(qf[ksl],     kf1, s1a, 0,0,0);
            s0b = __builtin_amdgcn_mfma_f32_16x16x32_f16(qf[8 + ksl], kg0, s0b, 0,0,0);
            s1b = __builtin_amdgcn_mfma_f32_16x16x32_f16(qf[8 + ksl], kg1, s1b, 0,0,0);
        }
        f32x4 s0, s1;
#pragma unroll
        for (int rr = 0; rr < 4; ++rr) { s0[rr] = s0a[rr] + s0b[rr]; s1[rr] = s1a[rr] + s1b[rr]; }

        // online softmax (row r = 4*qd+rr across quad's 16 lanes)
        float alpha[4];
        bool changed = false;
#pragma unroll
        for (int rr = 0; rr < 4; ++rr) {
            float v = fmaxf(s0[rr], s1[rr]);
            v = fmaxf(v, __shfl_xor(v, 1));
            v = fmaxf(v, __shfl_xor(v, 2));
            v = fmaxf(v, __shfl_xor(v, 4));
            v = fmaxf(v, __shfl_xor(v, 8));
            float mn = fmaxf(m_i[rr], v);
            alpha[rr] = __expf(m_i[rr] - mn);
            if (mn > m_i[rr]) changed = true;
            m_i[rr] = mn;
            s0[rr] = __expf(s0[rr] - mn);
            s1[rr] = __expf(s1[rr] - mn);
        }
        if (__any(changed)) {
#pragma unroll
            for (int nt = 0; nt < 32; ++nt)
#pragma unroll
                for (int rr = 0; rr < 4; ++rr) o[nt][rr] *= alpha[rr];
#pragma unroll
            for (int rr = 0; rr < 4; ++rr) o_l[rr] *= alpha[rr];
        }

        // P: C-layout -> A-layout via per-wave LDS
#pragma unroll
        for (int rr = 0; rr < 4; ++rr) {
            p_lds[w][qd*4 + rr][mrow]      = (f16)s0[rr];
            p_lds[w][qd*4 + rr][16 + mrow] = (f16)s1[rr];
        }
        f16x8 pf = *(const f16x8*)&p_lds[w][mrow][qd*8];
        o_l = __builtin_amdgcn_mfma_f32_16x16x32_f16(pf, ones, o_l, 0,0,0);

        // O += P @ V : 32 d-tiles (vb loop-invariant -> addresses hoistable)
#pragma unroll
        for (int nt = 0; nt < 32; ++nt) {
            int d = nt*16 + mrow;
            int chunk = d >> 8, dl = d & 255;
            f16x8 vf = *(const f16x8*)&vb[(chunk*1024 + dl*4 + ((qd + (dl >> 1)) & 3)) << 3];
            o[nt] = __builtin_amdgcn_mfma_f32_16x16x32_f16(pf, vf, o[nt], 0,0,0);
        }

        __syncthreads();   // A: all reads of kbuf/vbuf complete
        if (j < 63) {
            const size_t t0 = (size_t)(2*j + 2) * 2048;
            // V tile-pair via DMA (latency hides under the K stores below)
#pragma unroll
            for (int u = 0; u < 4; ++u) {
                const int ubase = (u*8 + w) * 64;
                gl_lds16(vSb + (t0 + ubase + lane)*8,        (f16*)&vbuf[0][ubase*8]);
                gl_lds16(vSb + (t0 + 2048 + ubase + lane)*8, (f16*)&vbuf[1][ubase*8]);
            }
            // K tile-pair from staged registers
#pragma unroll
            for (int u = 0; u < 4; ++u) {
                const int unit = u*512 + tid;
                *(f16x8*)&kbuf[0][unit*8] = skA[u];
                *(f16x8*)&kbuf[1][unit*8] = skB[u];
            }
        }
        __syncthreads();   // B: vmcnt(0)+lgkmcnt(0) drain -> tiles ready
    }

    // ---- merge even/odd softmax halves (pair w <-> w^4), reuse K/V LDS ----
    if (mrow == 0) {
#pragma unroll
        for (int rr = 0; rr < 4; ++rr) {
            mexch[w][qd][rr] = m_i[rr];
            lexch[w][qd][rr] = o_l[rr];
        }
    }
    __syncthreads();

    const int pw = w ^ 4;
    float al[4], l_tot[4];
#pragma unroll
    for (int rr = 0; rr < 4; ++rr) {
        float m_o = mexch[pw][qd][rr];
        float l_o = lexch[pw][qd][rr];
        float mm  = fmaxf(m_i[rr], m_o);
        al[rr]    = __expf(m_i[rr] - mm);
        l_tot[rr] = al[rr] * o_l[rr] + __expf(m_o - mm) * l_o;
    }
#pragma unroll
    for (int nt = 0; nt < 32; ++nt)
#pragma unroll
        for (int rr = 0; rr < 4; ++rr) o[nt][rr] *= al[rr];

    float* og = (g < 2) ? (float*)&kbuf[g][0] : (float*)&vbuf[g - 2][0]; // 32KB each
    if (half == 1) {
#pragma unroll
        for (int rr = 0; rr < 4; ++rr)
#pragma unroll
            for (int nt = 0; nt < 32; ++nt)
                og[(qd*4 + rr)*512 + nt*16 + mrow] = o[nt][rr];
    }
    __syncthreads();

    if (half == 0) {
#pragma unroll
        for (int rr = 0; rr < 4; ++rr) {
            float inv_l = 1.f / l_tot[rr];
            size_t grow = ((size_t)b*SEQ + qt*64 + g*16 + qd*4 + rr) * DIM;
#pragma unroll
            for (int nt = 0; nt < 32; ++nt) {
                int col = nt*16 + mrow;
                float val = (o[nt][rr] + og[(qd*4 + rr)*512 + col]) * inv_l
                          + (float)qvh[grow + col];
                ao[grow + col] = (f16)val;
            }
        }
    }
}

// ---------------------------------------------------------------------------
// Final linear: out[m,n] = sum_k ao[m,k]*Wf[n,k] + bf[n]  (f32 out)
// ---------------------------------------------------------------------------
__global__ __launch_bounds__(256) void final_gemm(
    const f16* __restrict__ ao, const float* __restrict__ Wf,
    const float* __restrict__ bf, float* __restrict__ out)
{
    __shared__ __attribute__((aligned(16))) f16 a_lds[128][40];
    __shared__ __attribute__((aligned(16))) f16 b_lds[128][40];

    const int m0 = blockIdx.y * 128, n0 = blockIdx.x * 128;
    const int tid = threadIdx.x, lane = tid & 63, wv = tid >> 6;
    const int wm = wv >> 1, wn = wv & 1, mrow = lane & 15, qd = lane >> 4;

    f32x4 acc[4][4];
#pragma unroll
    for (int mt = 0; mt < 4; ++mt)
#pragma unroll
        for (int nt = 0; nt < 4; ++nt) acc[mt][nt] = (f32x4){0.f,0.f,0.f,0.f};

    float bv[4];
#pragma unroll
    for (int nt = 0; nt < 4; ++nt) bv[nt] = bf[n0 + wn*64 + nt*16 + mrow];

    for (int k0 = 0; k0 < DIM; k0 += 32) {
        __syncthreads();
#pragma unroll
        for (int i = 0; i < 2; ++i) {
            int c = i*256 + tid;
            int row = c >> 2, c8 = c & 3;
            *(f16x8*)&a_lds[row][c8*8] =
                *(const f16x8*)(ao + (size_t)(m0+row)*DIM + k0 + c8*8);
        }
#pragma unroll
        for (int i = 0; i < 4; ++i) {
            int c = i*256 + tid;
            int row = c >> 3, c4 = c & 7;
            float4 v = *(const float4*)(Wf + (size_t)(n0+row)*DIM + k0 + c4*4);
            f16x4 hh = { (f16)v.x, (f16)v.y, (f16)v.z, (f16)v.w };
            *(f16x4*)&b_lds[row][c4*4] = hh;
        }
        __syncthreads();
        f16x8 af[4], bfr[4];
#pragma unroll
        for (int mt = 0; mt < 4; ++mt) af[mt]  = *(const f16x8*)&a_lds[wm*64 + mt*16 + mrow][qd*8];
#pragma unroll
        for (int nt = 0; nt < 4; ++nt) bfr[nt] = *(const f16x8*)&b_lds[wn*64 + nt*16 + mrow][qd*8];
#pragma unroll
        for (int mt = 0; mt < 4; ++mt)
#pragma unroll
            for (int nt = 0; nt < 4; ++nt)
                acc[mt][nt] = __builtin_amdgcn_mfma_f32_16x16x32_f16(af[mt], bfr[nt], acc[mt][nt], 0,0,0);
    }
#pragma unroll
    for (int mt = 0; mt < 4; ++mt)
#pragma unroll
        for (int r = 0; r < 4; ++r) {
            size_t grow = (size_t)(m0 + wm*64 + mt*16 + qd*4 + r) * DIM;
#pragma unroll
            for (int nt = 0; nt < 4; ++nt) {
                int col = n0 + wn*64 + nt*16 + mrow;
                out[grow + col] = acc[mt][nt][r] + bv[nt];
            }
        }
}

// ---------------------------------------------------------------------------
extern "C" void kernel_launch(void* const* d_in, const int* in_sizes, int n_in,
                              void* d_out, int out_size, void* d_ws, size_t ws_size,
                              hipStream_t stream)
{
    const float* x   = (const float*)d_in[0];
    const float* y   = (const float*)d_in[1];
    const float* Wq  = (const float*)d_in[2];
    const float* bq  = (const float*)d_in[3];
    const float* Wqv = (const float*)d_in[4];
    const float* bqv = (const float*)d_in[5];
    const float* Wk  = (const float*)d_in[6];
    const float* bk  = (const float*)d_in[7];
    const float* Wkv = (const float*)d_in[8];
    const float* bkv = (const float*)d_in[9];
    const float* Wf  = (const float*)d_in[10];
    const float* bf  = (const float*)d_in[11];
    float* out = (float*)d_out;

    f16* qh  = (f16*)d_ws;       // NEL f16 each; 84 MB total
    f16* qvh = qh  + NEL;
    f16* kS  = qvh + NEL;
    f16* vS  = kS  + NEL;
    f16* aob = vS  + NEL;

    proj_gemm<<<dim3(4, 128, 4), 256, 0, stream>>>(
        x, y, Wq, bq, Wqv, bqv, Wk, bk, Wkv, bkv, qh, qvh, kS, vS);
    attn_kernel<<<dim3(256), 512, 0, stream>>>(qh, kS, vS, qvh, aob);
    final_gemm<<<dim3(4, 128), 256, 0, stream>>>(aob, Wf, bf, out);
}

// Round 2
// 536.644 us; speedup vs baseline: 1.3470x; 1.3470x over previous
//
#include <hip/hip_runtime.h>

typedef _Float16 f16;
typedef _Float16 f16x8 __attribute__((ext_vector_type(8)));
typedef _Float16 f16x4 __attribute__((ext_vector_type(4)));
typedef float    f32x4 __attribute__((ext_vector_type(4)));

#define NB 4
#define SEQ 4096
#define DIM 512
#define MTOT (NB*SEQ)   // 16384
#define NEL ((size_t)MTOT*DIM)

// ---------------------------------------------------------------------------
// Projection GEMM: out[m,n] = f16( sum_k A[m,k] * W[n,k] + bias[n] )
// p: 0:q natural  1:qv natural  2:k K-swizzled  3:kv V-swizzled
// Swizzled layouts (per batch, per 32-row kv tile t, per 256-D chunk), unit=8 f16:
//  K: unit = t*2048 + chunk*1024 + n*32 + ((ksl*4+q+n)&31), elem j
//     where d = chunk*256 + ksl*32 + q*8 + j, n = s&31
//  V: unit = t*2048 + chunk*1024 + dl*4 + ((q+(dl>>1))&3), elem j
//     where s = t*32 + q*8 + j, dl = d&255
// ---------------------------------------------------------------------------
__global__ __launch_bounds__(256) void proj_gemm(
    const float* __restrict__ x, const float* __restrict__ y,
    const float* __restrict__ Wq, const float* __restrict__ bq,
    const float* __restrict__ Wqv, const float* __restrict__ bqv,
    const float* __restrict__ Wk, const float* __restrict__ bk,
    const float* __restrict__ Wkv, const float* __restrict__ bkv,
    f16* __restrict__ qh, f16* __restrict__ qvh,
    f16* __restrict__ kS, f16* __restrict__ vS)
{
    __shared__ __attribute__((aligned(16))) f16 a_lds[128][40];
    __shared__ __attribute__((aligned(16))) f16 b_lds[128][40];

    const int p = blockIdx.z;
    const float* A    = (p < 2) ? x : y;
    const float* W    = (p==0)?Wq:(p==1)?Wqv:(p==2)?Wk:Wkv;
    const float* bias = (p==0)?bq:(p==1)?bqv:(p==2)?bk:bkv;

    const int m0 = blockIdx.y * 128, n0 = blockIdx.x * 128;
    const int tid = threadIdx.x, lane = tid & 63, wv = tid >> 6;
    const int wm = wv >> 1, wn = wv & 1, mrow = lane & 15, qd = lane >> 4;

    f32x4 acc[4][4];
#pragma unroll
    for (int mt = 0; mt < 4; ++mt)
#pragma unroll
        for (int nt = 0; nt < 4; ++nt) acc[mt][nt] = (f32x4){0.f,0.f,0.f,0.f};

    float bv[4];
#pragma unroll
    for (int nt = 0; nt < 4; ++nt) bv[nt] = bias[n0 + wn*64 + nt*16 + mrow];

    for (int k0 = 0; k0 < DIM; k0 += 32) {
        __syncthreads();
#pragma unroll
        for (int i = 0; i < 4; ++i) {
            int c = i*256 + tid;
            int row = c >> 3, c4 = c & 7;
            float4 v = *(const float4*)(A + (size_t)(m0+row)*DIM + k0 + c4*4);
            f16x4 hh = { (f16)v.x, (f16)v.y, (f16)v.z, (f16)v.w };
            *(f16x4*)&a_lds[row][c4*4] = hh;
        }
#pragma unroll
        for (int i = 0; i < 4; ++i) {
            int c = i*256 + tid;
            int row = c >> 3, c4 = c & 7;
            float4 v = *(const float4*)(W + (size_t)(n0+row)*DIM + k0 + c4*4);
            f16x4 hh = { (f16)v.x, (f16)v.y, (f16)v.z, (f16)v.w };
            *(f16x4*)&b_lds[row][c4*4] = hh;
        }
        __syncthreads();
        f16x8 af[4], bfr[4];
#pragma unroll
        for (int mt = 0; mt < 4; ++mt) af[mt]  = *(const f16x8*)&a_lds[wm*64 + mt*16 + mrow][qd*8];
#pragma unroll
        for (int nt = 0; nt < 4; ++nt) bfr[nt] = *(const f16x8*)&b_lds[wn*64 + nt*16 + mrow][qd*8];
#pragma unroll
        for (int mt = 0; mt < 4; ++mt)
#pragma unroll
            for (int nt = 0; nt < 4; ++nt)
                acc[mt][nt] = __builtin_amdgcn_mfma_f32_16x16x32_f16(af[mt], bfr[nt], acc[mt][nt], 0,0,0);
    }

#pragma unroll
    for (int mt = 0; mt < 4; ++mt)
#pragma unroll
        for (int r = 0; r < 4; ++r) {
            int g = m0 + wm*64 + mt*16 + qd*4 + r;
#pragma unroll
            for (int nt = 0; nt < 4; ++nt) {
                int d = n0 + wn*64 + nt*16 + mrow;
                f16 val = (f16)(acc[mt][nt][r] + bv[nt]);
                if (p == 0) {
                    qh[(size_t)g*DIM + d] = val;
                } else if (p == 1) {
                    qvh[(size_t)g*DIM + d] = val;
                } else if (p == 2) {
                    int b = g >> 12, s = g & 4095;
                    int t = s >> 5, n = s & 31;
                    int chunk = d >> 8, ksl = (d >> 5) & 7, q = (d >> 3) & 3, j = d & 7;
                    size_t idx = (((size_t)((b*128 + t)*2048 + chunk*1024
                                   + n*32 + ((ksl*4 + q + n) & 31))) << 3) + j;
                    kS[idx] = val;
                } else {
                    int b = g >> 12, s = g & 4095;
                    int t = s >> 5, q = (s >> 3) & 3, j = s & 7;
                    int chunk = d >> 8, dl = d & 255;
                    size_t idx = (((size_t)((b*128 + t)*2048 + chunk*1024
                                   + dl*4 + ((q + (dl >> 1)) & 3))) << 3) + j;
                    vS[idx] = val;
                }
            }
        }
}

// ---------------------------------------------------------------------------
// global -> LDS direct DMA, 16B per lane. LDS dest is wave-uniform base;
// HW adds lane*16. Global src is per-lane.
// ---------------------------------------------------------------------------
__device__ __forceinline__ void gl_lds16(const f16* g, f16* l)
{
    __builtin_amdgcn_global_load_lds(
        (const __attribute__((address_space(1))) void*)g,
        (__attribute__((address_space(3))) void*)l, 16, 0, 0);
}

// ---------------------------------------------------------------------------
// Flash attention v3: 256 blocks (1/CU), 512 threads / 8 waves = 2 waves/SIMD.
// Wave pair (qg, qg+4) shares 16 Q rows and splits the FEATURE dim:
//   QK^T: each wave reduces its 256-d half of K (qf[8] = 32 VGPRs), partial
//         16x32 scores exchanged via LDS and summed (exact, f32).
//   softmax: duplicated per pair (cheap VALU).
//   PV:   each wave accumulates its 256-d output half (o[16] = 64 AGPRs).
// Per-wave total regs ~170 << 256 cap at waves_per_eu=2 -> no spill (v2's
// failure mode). K and V staged by global_load_lds (zero staging VGPRs),
// double-buffered, issued at iteration top; vmcnt drained at the barriers.
// ---------------------------------------------------------------------------
__global__ __launch_bounds__(512, 2) void attn_kernel(
    const f16* __restrict__ qh, const f16* __restrict__ kS,
    const f16* __restrict__ vS, const f16* __restrict__ qvh,
    f16* __restrict__ ao)
{
    __shared__ __attribute__((aligned(16))) f16 kbuf[2][16384];  // 2 x 32KB
    __shared__ __attribute__((aligned(16))) f16 vbuf[2][16384];  // 2 x 32KB
    __shared__ __attribute__((aligned(16))) f16 p_lds[8][16][40]; // 10KB
    __shared__ __attribute__((aligned(16))) f32x4 sx[4][2][2][64]; // 16KB

    const int xcd = blockIdx.x & 7;
    const int b   = xcd >> 1;                          // batch -> XCD pair
    const int qt  = (blockIdx.x >> 3) * 2 + (xcd & 1); // 0..63
    const int tid = threadIdx.x, lane = tid & 63, w = tid >> 6;
    const int qg = w & 3, h = w >> 2;                  // Q group / d-half
    const int mrow = lane & 15, qd = lane >> 4;

    const f16* kSb = kS + ((size_t)b << 21);
    const f16* vSb = vS + ((size_t)b << 21);

    // Q fragments for this wave's 256-d half (A-layout)
    const size_t qrow = ((size_t)b*SEQ + qt*64 + qg*16 + mrow) * DIM;
    f16x8 qf[8];
#pragma unroll
    for (int i = 0; i < 8; ++i)
        qf[i] = *(const f16x8*)(qh + qrow + (h*8 + i)*32 + qd*8);

    f32x4 o[16];
#pragma unroll
    for (int nt = 0; nt < 16; ++nt) o[nt] = (f32x4){0.f,0.f,0.f,0.f};
    f32x4 o_l = (f32x4){0.f,0.f,0.f,0.f};
    float m_i[4] = {-INFINITY,-INFINITY,-INFINITY,-INFINITY};
    const f16x8 ones = {(f16)1.f,(f16)1.f,(f16)1.f,(f16)1.f,
                        (f16)1.f,(f16)1.f,(f16)1.f,(f16)1.f};

    // prologue: DMA tile 0 into buffer 0
#pragma unroll
    for (int u = 0; u < 4; ++u) {
        const int ubase = (u*8 + w) * 64;              // wave-uniform unit base
        gl_lds16(kSb + (size_t)(ubase + lane)*8, (f16*)&kbuf[0][ubase*8]);
        gl_lds16(vSb + (size_t)(ubase + lane)*8, (f16*)&vbuf[0][ubase*8]);
    }
    __syncthreads();

    const int n0a = mrow, n1a = 16 + mrow;
    const int cbase = h * 1024;                        // unit base of d-half chunk

    for (int j = 0; j < 128; ++j) {
        const f16* kb = &kbuf[j & 1][0];
        const f16* vb = &vbuf[j & 1][0];

        // issue next tile's DMA NOW (into the other buffer; its readers
        // finished before the barrier that ended iter j-1)
        if (j < 127) {
            const size_t t0 = (size_t)(j + 1) * 2048;
            f16* kd = &kbuf[(j + 1) & 1][0];
            f16* vd = &vbuf[(j + 1) & 1][0];
#pragma unroll
            for (int u = 0; u < 4; ++u) {
                const int ubase = (u*8 + w) * 64;
                gl_lds16(kSb + (t0 + ubase + lane)*8, kd + ubase*8);
                gl_lds16(vSb + (t0 + ubase + lane)*8, vd + ubase*8);
            }
        }

        // partial S = Q_half K_half^T : 16x32 per wave, 16 MFMA
        f32x4 s0 = (f32x4){0.f,0.f,0.f,0.f}, s1 = s0;
#pragma unroll
        for (int ksl = 0; ksl < 8; ++ksl) {
            f16x8 kf0 = *(const f16x8*)&kb[(cbase + n0a*32 + ((ksl*4 + qd + n0a) & 31)) << 3];
            f16x8 kf1 = *(const f16x8*)&kb[(cbase + n1a*32 + ((ksl*4 + qd + n1a) & 31)) << 3];
            s0 = __builtin_amdgcn_mfma_f32_16x16x32_f16(qf[ksl], kf0, s0, 0,0,0);
            s1 = __builtin_amdgcn_mfma_f32_16x16x32_f16(qf[ksl], kf1, s1, 0,0,0);
        }

        // exchange partials within the pair and sum (f32, exact)
        sx[qg][h][0][lane] = s0;
        sx[qg][h][1][lane] = s1;
        __syncthreads();   // BAR1 (also lands this iter's early DMA wait-point)
        {
            f32x4 t0v = sx[qg][h ^ 1][0][lane];
            f32x4 t1v = sx[qg][h ^ 1][1][lane];
#pragma unroll
            for (int rr = 0; rr < 4; ++rr) { s0[rr] += t0v[rr]; s1[rr] += t1v[rr]; }
        }

        // online softmax (row r = 4*qd+rr across quad's 16 lanes); dup per pair
        float alpha[4];
        bool changed = false;
#pragma unroll
        for (int rr = 0; rr < 4; ++rr) {
            float v = fmaxf(s0[rr], s1[rr]);
            v = fmaxf(v, __shfl_xor(v, 1));
            v = fmaxf(v, __shfl_xor(v, 2));
            v = fmaxf(v, __shfl_xor(v, 4));
            v = fmaxf(v, __shfl_xor(v, 8));
            float mn = fmaxf(m_i[rr], v);
            alpha[rr] = __expf(m_i[rr] - mn);
            if (mn > m_i[rr]) changed = true;
            m_i[rr] = mn;
            s0[rr] = __expf(s0[rr] - mn);
            s1[rr] = __expf(s1[rr] - mn);
        }
        if (__any(changed)) {
#pragma unroll
            for (int nt = 0; nt < 16; ++nt)
#pragma unroll
                for (int rr = 0; rr < 4; ++rr) o[nt][rr] *= alpha[rr];
#pragma unroll
            for (int rr = 0; rr < 4; ++rr) o_l[rr] *= alpha[rr];
        }

        // P: C-layout -> A-layout via per-wave LDS (no cross-wave sync needed)
#pragma unroll
        for (int rr = 0; rr < 4; ++rr) {
            p_lds[w][qd*4 + rr][mrow]      = (f16)s0[rr];
            p_lds[w][qd*4 + rr][16 + mrow] = (f16)s1[rr];
        }
        f16x8 pf = *(const f16x8*)&p_lds[w][mrow][qd*8];
        o_l = __builtin_amdgcn_mfma_f32_16x16x32_f16(pf, ones, o_l, 0,0,0);

        // O_half += P @ V_half : 16 d-tiles
#pragma unroll
        for (int nt = 0; nt < 16; ++nt) {
            int dl = nt*16 + mrow;                     // d = h*256 + dl
            f16x8 vf = *(const f16x8*)&vb[(cbase + dl*4 + ((qd + (dl >> 1)) & 3)) << 3];
            o[nt] = __builtin_amdgcn_mfma_f32_16x16x32_f16(pf, vf, o[nt], 0,0,0);
        }

        __syncthreads();   // BAR2: buffer reads done + next tile's DMA drained
    }

    // epilogue: each wave owns rows [qg*16,+16) x cols [h*256,+256) fully
#pragma unroll
    for (int rr = 0; rr < 4; ++rr) {
        float inv_l = 1.f / o_l[rr];
        size_t grow = ((size_t)b*SEQ + qt*64 + qg*16 + qd*4 + rr) * DIM + h*256;
#pragma unroll
        for (int nt = 0; nt < 16; ++nt) {
            int col = nt*16 + mrow;
            float val = o[nt][rr] * inv_l + (float)qvh[grow + col];
            ao[grow + col] = (f16)val;
        }
    }
}

// ---------------------------------------------------------------------------
// Final linear: out[m,n] = sum_k ao[m,k]*Wf[n,k] + bf[n]  (f32 out)
// ---------------------------------------------------------------------------
__global__ __launch_bounds__(256) void final_gemm(
    const f16* __restrict__ ao, const float* __restrict__ Wf,
    const float* __restrict__ bf, float* __restrict__ out)
{
    __shared__ __attribute__((aligned(16))) f16 a_lds[128][40];
    __shared__ __attribute__((aligned(16))) f16 b_lds[128][40];

    const int m0 = blockIdx.y * 128, n0 = blockIdx.x * 128;
    const int tid = threadIdx.x, lane = tid & 63, wv = tid >> 6;
    const int wm = wv >> 1, wn = wv & 1, mrow = lane & 15, qd = lane >> 4;

    f32x4 acc[4][4];
#pragma unroll
    for (int mt = 0; mt < 4; ++mt)
#pragma unroll
        for (int nt = 0; nt < 4; ++nt) acc[mt][nt] = (f32x4){0.f,0.f,0.f,0.f};

    float bv[4];
#pragma unroll
    for (int nt = 0; nt < 4; ++nt) bv[nt] = bf[n0 + wn*64 + nt*16 + mrow];

    for (int k0 = 0; k0 < DIM; k0 += 32) {
        __syncthreads();
#pragma unroll
        for (int i = 0; i < 2; ++i) {
            int c = i*256 + tid;
            int row = c >> 2, c8 = c & 3;
            *(f16x8*)&a_lds[row][c8*8] =
                *(const f16x8*)(ao + (size_t)(m0+row)*DIM + k0 + c8*8);
        }
#pragma unroll
        for (int i = 0; i < 4; ++i) {
            int c = i*256 + tid;
            int row = c >> 3, c4 = c & 7;
            float4 v = *(const float4*)(Wf + (size_t)(n0+row)*DIM + k0 + c4*4);
            f16x4 hh = { (f16)v.x, (f16)v.y, (f16)v.z, (f16)v.w };
            *(f16x4*)&b_lds[row][c4*4] = hh;
        }
        __syncthreads();
        f16x8 af[4], bfr[4];
#pragma unroll
        for (int mt = 0; mt < 4; ++mt) af[mt]  = *(const f16x8*)&a_lds[wm*64 + mt*16 + mrow][qd*8];
#pragma unroll
        for (int nt = 0; nt < 4; ++nt) bfr[nt] = *(const f16x8*)&b_lds[wn*64 + nt*16 + mrow][qd*8];
#pragma unroll
        for (int mt = 0; mt < 4; ++mt)
#pragma unroll
            for (int nt = 0; nt < 4; ++nt)
                acc[mt][nt] = __builtin_amdgcn_mfma_f32_16x16x32_f16(af[mt], bfr[nt], acc[mt][nt], 0,0,0);
    }
#pragma unroll
    for (int mt = 0; mt < 4; ++mt)
#pragma unroll
        for (int r = 0; r < 4; ++r) {
            size_t grow = (size_t)(m0 + wm*64 + mt*16 + qd*4 + r) * DIM;
#pragma unroll
            for (int nt = 0; nt < 4; ++nt) {
                int col = n0 + wn*64 + nt*16 + mrow;
                out[grow + col] = acc[mt][nt][r] + bv[nt];
            }
        }
}

// ---------------------------------------------------------------------------
extern "C" void kernel_launch(void* const* d_in, const int* in_sizes, int n_in,
                              void* d_out, int out_size, void* d_ws, size_t ws_size,
                              hipStream_t stream)
{
    const float* x   = (const float*)d_in[0];
    const float* y   = (const float*)d_in[1];
    const float* Wq  = (const float*)d_in[2];
    const float* bq  = (const float*)d_in[3];
    const float* Wqv = (const float*)d_in[4];
    const float* bqv = (const float*)d_in[5];
    const float* Wk  = (const float*)d_in[6];
    const float* bk  = (const float*)d_in[7];
    const float* Wkv = (const float*)d_in[8];
    const float* bkv = (const float*)d_in[9];
    const float* Wf  = (const float*)d_in[10];
    const float* bf  = (const float*)d_in[11];
    float* out = (float*)d_out;

    f16* qh  = (f16*)d_ws;       // NEL f16 each; 80 MB total
    f16* qvh = qh  + NEL;
    f16* kS  = qvh + NEL;
    f16* vS  = kS  + NEL;
    f16* aob = vS  + NEL;

    proj_gemm<<<dim3(4, 128, 4), 256, 0, stream>>>(
        x, y, Wq, bq, Wqv, bqv, Wk, bk, Wkv, bkv, qh, qvh, kS, vS);
    attn_kernel<<<dim3(256), 512, 0, stream>>>(qh, kS, vS, qvh, aob);
    final_gemm<<<dim3(4, 128), 256, 0, stream>>>(aob, Wf, bf, out);
}

// Round 3
// 531.412 us; speedup vs baseline: 1.3602x; 1.0098x over previous
//
#include <hip/hip_runtime.h>

typedef _Float16 f16;
typedef _Float16 f16x8 __attribute__((ext_vector_type(8)));
typedef _Float16 f16x4 __attribute__((ext_vector_type(4)));
typedef float    f32x4 __attribute__((ext_vector_type(4)));

#define NB 4
#define SEQ 4096
#define DIM 512
#define MTOT (NB*SEQ)   // 16384
#define NEL ((size_t)MTOT*DIM)

// ---------------------------------------------------------------------------
// Projection GEMM: out[m,n] = f16( sum_k A[m,k] * W[n,k] + bias[n] )
// p: 0:q natural  1:qv natural  2:k K-swizzled  3:kv V-swizzled
// Swizzled layouts (per batch, per 32-row kv tile t, per 256-D chunk), unit=8 f16:
//  K: unit = t*2048 + chunk*1024 + n*32 + ((ksl*4+q+n)&31), elem j
//     where d = chunk*256 + ksl*32 + q*8 + j, n = s&31
//  V: unit = t*2048 + chunk*1024 + dl*4 + ((q+(dl>>1))&3), elem j
//     where s = t*32 + q*8 + j, dl = d&255
// ---------------------------------------------------------------------------
__global__ __launch_bounds__(256) void proj_gemm(
    const float* __restrict__ x, const float* __restrict__ y,
    const float* __restrict__ Wq, const float* __restrict__ bq,
    const float* __restrict__ Wqv, const float* __restrict__ bqv,
    const float* __restrict__ Wk, const float* __restrict__ bk,
    const float* __restrict__ Wkv, const float* __restrict__ bkv,
    f16* __restrict__ qh, f16* __restrict__ qvh,
    f16* __restrict__ kS, f16* __restrict__ vS)
{
    __shared__ __attribute__((aligned(16))) f16 a_lds[128][40];
    __shared__ __attribute__((aligned(16))) f16 b_lds[128][40];

    const int p = blockIdx.z;
    const float* A    = (p < 2) ? x : y;
    const float* W    = (p==0)?Wq:(p==1)?Wqv:(p==2)?Wk:Wkv;
    const float* bias = (p==0)?bq:(p==1)?bqv:(p==2)?bk:bkv;

    const int m0 = blockIdx.y * 128, n0 = blockIdx.x * 128;
    const int tid = threadIdx.x, lane = tid & 63, wv = tid >> 6;
    const int wm = wv >> 1, wn = wv & 1, mrow = lane & 15, qd = lane >> 4;

    f32x4 acc[4][4];
#pragma unroll
    for (int mt = 0; mt < 4; ++mt)
#pragma unroll
        for (int nt = 0; nt < 4; ++nt) acc[mt][nt] = (f32x4){0.f,0.f,0.f,0.f};

    float bv[4];
#pragma unroll
    for (int nt = 0; nt < 4; ++nt) bv[nt] = bias[n0 + wn*64 + nt*16 + mrow];

    for (int k0 = 0; k0 < DIM; k0 += 32) {
        __syncthreads();
#pragma unroll
        for (int i = 0; i < 4; ++i) {
            int c = i*256 + tid;
            int row = c >> 3, c4 = c & 7;
            float4 v = *(const float4*)(A + (size_t)(m0+row)*DIM + k0 + c4*4);
            f16x4 hh = { (f16)v.x, (f16)v.y, (f16)v.z, (f16)v.w };
            *(f16x4*)&a_lds[row][c4*4] = hh;
        }
#pragma unroll
        for (int i = 0; i < 4; ++i) {
            int c = i*256 + tid;
            int row = c >> 3, c4 = c & 7;
            float4 v = *(const float4*)(W + (size_t)(n0+row)*DIM + k0 + c4*4);
            f16x4 hh = { (f16)v.x, (f16)v.y, (f16)v.z, (f16)v.w };
            *(f16x4*)&b_lds[row][c4*4] = hh;
        }
        __syncthreads();
        f16x8 af[4], bfr[4];
#pragma unroll
        for (int mt = 0; mt < 4; ++mt) af[mt]  = *(const f16x8*)&a_lds[wm*64 + mt*16 + mrow][qd*8];
#pragma unroll
        for (int nt = 0; nt < 4; ++nt) bfr[nt] = *(const f16x8*)&b_lds[wn*64 + nt*16 + mrow][qd*8];
#pragma unroll
        for (int mt = 0; mt < 4; ++mt)
#pragma unroll
            for (int nt = 0; nt < 4; ++nt)
                acc[mt][nt] = __builtin_amdgcn_mfma_f32_16x16x32_f16(af[mt], bfr[nt], acc[mt][nt], 0,0,0);
    }

#pragma unroll
    for (int mt = 0; mt < 4; ++mt)
#pragma unroll
        for (int r = 0; r < 4; ++r) {
            int g = m0 + wm*64 + mt*16 + qd*4 + r;
#pragma unroll
            for (int nt = 0; nt < 4; ++nt) {
                int d = n0 + wn*64 + nt*16 + mrow;
                f16 val = (f16)(acc[mt][nt][r] + bv[nt]);
                if (p == 0) {
                    qh[(size_t)g*DIM + d] = val;
                } else if (p == 1) {
                    qvh[(size_t)g*DIM + d] = val;
                } else if (p == 2) {
                    int b = g >> 12, s = g & 4095;
                    int t = s >> 5, n = s & 31;
                    int chunk = d >> 8, ksl = (d >> 5) & 7, q = (d >> 3) & 3, j = d & 7;
                    size_t idx = (((size_t)((b*128 + t)*2048 + chunk*1024
                                   + n*32 + ((ksl*4 + q + n) & 31))) << 3) + j;
                    kS[idx] = val;
                } else {
                    int b = g >> 12, s = g & 4095;
                    int t = s >> 5, q = (s >> 3) & 3, j = s & 7;
                    int chunk = d >> 8, dl = d & 255;
                    size_t idx = (((size_t)((b*128 + t)*2048 + chunk*1024
                                   + dl*4 + ((q + (dl >> 1)) & 3))) << 3) + j;
                    vS[idx] = val;
                }
            }
        }
}

// ---------------------------------------------------------------------------
// global -> LDS direct DMA, 16B per lane. LDS dest is wave-uniform base;
// HW adds lane*16. Global src is per-lane.
// ---------------------------------------------------------------------------
__device__ __forceinline__ void gl_lds16(const f16* g, f16* l)
{
    __builtin_amdgcn_global_load_lds(
        (const __attribute__((address_space(1))) void*)g,
        (__attribute__((address_space(3))) void*)l, 16, 0, 0);
}

// ---------------------------------------------------------------------------
// Flash attention v4: 256 blocks (1/CU), 512 threads / 8 waves = 2 waves/SIMD.
// D-split pairs (qg, qg+4) as in v3, but ONE barrier per iteration:
// software-pipelined partial-S. Iteration j:
//   top:  DMA K(j+2)->kbuf[j&1], V(j+1)->vbuf[(j+1)&1]   (full-body cover)
//   read partner S_j from xch[j&1] (written iter j-1) + own regs -> full S_j
//   softmax_j (defer-max THR=8), P_j -> p-slice of xch[j&1] (slot reuse), PV_j
//   partial S_{j+1} from kbuf[(j+1)&1] -> regs + xch[(j+1)&1]
//   tail: __syncthreads()   (sole barrier; drains loads with ~full-body cover)
// Exchange regions double as per-wave P-transpose scratch: wave (qg,h)'s
// p-slice = slot (qg,h^1) it alone just consumed (self-ordered in-wave).
// LDS: 64K kbuf + 64K vbuf + 32K xch = 163840 B (exactly 160 KiB).
// ---------------------------------------------------------------------------
__global__ __launch_bounds__(512, 2) void attn_kernel(
    const f16* __restrict__ qh, const f16* __restrict__ kS,
    const f16* __restrict__ vS, const f16* __restrict__ qvh,
    f16* __restrict__ ao)
{
    __shared__ __attribute__((aligned(16))) f16 kbuf[2][16384];   // 2 x 32KB
    __shared__ __attribute__((aligned(16))) f16 vbuf[2][16384];   // 2 x 32KB
    __shared__ __attribute__((aligned(16))) float xch[2][4][2][512]; // 32KB

    const int xcd = blockIdx.x & 7;
    const int b   = xcd >> 1;                          // batch -> XCD pair
    const int qt  = (blockIdx.x >> 3) * 2 + (xcd & 1); // 0..63
    const int tid = threadIdx.x, lane = tid & 63, w = tid >> 6;
    const int qg = w & 3, h = w >> 2;                  // Q group / d-half
    const int mrow = lane & 15, qd = lane >> 4;

    const f16* kSb = kS + ((size_t)b << 21);
    const f16* vSb = vS + ((size_t)b << 21);

    // Q fragments for this wave's 256-d half (A-layout)
    const size_t qrow = ((size_t)b*SEQ + qt*64 + qg*16 + mrow) * DIM;
    f16x8 qf[8];
#pragma unroll
    for (int i = 0; i < 8; ++i)
        qf[i] = *(const f16x8*)(qh + qrow + (h*8 + i)*32 + qd*8);

    f32x4 o[16];
#pragma unroll
    for (int nt = 0; nt < 16; ++nt) o[nt] = (f32x4){0.f,0.f,0.f,0.f};
    f32x4 o_l = (f32x4){0.f,0.f,0.f,0.f};
    float m_i[4] = {-INFINITY,-INFINITY,-INFINITY,-INFINITY};
    const f16x8 ones = {(f16)1.f,(f16)1.f,(f16)1.f,(f16)1.f,
                        (f16)1.f,(f16)1.f,(f16)1.f,(f16)1.f};

    const int n0a = mrow, n1a = 16 + mrow;
    const int cbase = h * 1024;                        // unit base of d-half chunk

    // prologue: DMA K0->kbuf0, V0->vbuf0, K1->kbuf1 (12 DMA/wave)
#pragma unroll
    for (int u = 0; u < 4; ++u) {
        const int ub = (u*8 + w) * 64;
        gl_lds16(kSb + (size_t)(ub + lane)*8,        (f16*)&kbuf[0][ub*8]);
    }
#pragma unroll
    for (int u = 0; u < 4; ++u) {
        const int ub = (u*8 + w) * 64;
        gl_lds16(vSb + (size_t)(ub + lane)*8,        (f16*)&vbuf[0][ub*8]);
    }
#pragma unroll
    for (int u = 0; u < 4; ++u) {
        const int ub = (u*8 + w) * 64;
        gl_lds16(kSb + (size_t)(2048 + ub + lane)*8, (f16*)&kbuf[1][ub*8]);
    }
    __syncthreads();

    // partial S_0 from kbuf[0]
    f32x4 s0p = (f32x4){0.f,0.f,0.f,0.f}, s1p = s0p;
    {
        const f16* kb = &kbuf[0][0];
        __builtin_amdgcn_s_setprio(1);
#pragma unroll
        for (int ksl = 0; ksl < 8; ++ksl) {
            f16x8 kf0 = *(const f16x8*)&kb[(cbase + n0a*32 + ((ksl*4 + qd + n0a) & 31)) << 3];
            f16x8 kf1 = *(const f16x8*)&kb[(cbase + n1a*32 + ((ksl*4 + qd + n1a) & 31)) << 3];
            s0p = __builtin_amdgcn_mfma_f32_16x16x32_f16(qf[ksl], kf0, s0p, 0,0,0);
            s1p = __builtin_amdgcn_mfma_f32_16x16x32_f16(qf[ksl], kf1, s1p, 0,0,0);
        }
        __builtin_amdgcn_s_setprio(0);
        f32x4* slot0 = (f32x4*)&xch[0][qg][h][0];
        slot0[lane]      = s0p;
        slot0[64 + lane] = s1p;
    }
    __syncthreads();

    for (int j = 0; j < 128; ++j) {
        // --- top: prefetch K(j+2) and V(j+1); drained at THIS iter's tail ---
        {
            const size_t tk = (size_t)((j + 2) & 127) * 2048;
            const size_t tv = (size_t)((j + 1) & 127) * 2048;
            f16* kd = &kbuf[j & 1][0];
            f16* vd = &vbuf[(j + 1) & 1][0];
#pragma unroll
            for (int u = 0; u < 4; ++u) {
                const int ub = (u*8 + w) * 64;
                gl_lds16(kSb + (tk + ub + lane)*8, kd + ub*8);
                gl_lds16(vSb + (tv + ub + lane)*8, vd + ub*8);
            }
        }

        // --- exchange: partner partial S_j (written iter j-1) + own regs ---
        float* slotr = &xch[j & 1][qg][h ^ 1][0];
        f32x4 s0 = ((const f32x4*)slotr)[lane];
        f32x4 s1 = ((const f32x4*)slotr)[64 + lane];
#pragma unroll
        for (int rr = 0; rr < 4; ++rr) { s0[rr] += s0p[rr]; s1[rr] += s1p[rr]; }

        // --- online softmax with defer-max (THR=8) ---
        float pm[4];
        bool need = false;
#pragma unroll
        for (int rr = 0; rr < 4; ++rr) {
            float v = fmaxf(s0[rr], s1[rr]);
            v = fmaxf(v, __shfl_xor(v, 1));
            v = fmaxf(v, __shfl_xor(v, 2));
            v = fmaxf(v, __shfl_xor(v, 4));
            v = fmaxf(v, __shfl_xor(v, 8));
            pm[rr] = v;
            if (v > m_i[rr] + 8.f) need = true;
        }
        if (__any(need)) {
#pragma unroll
            for (int rr = 0; rr < 4; ++rr) {
                float mn = fmaxf(m_i[rr], pm[rr]);
                float alpha = __expf(m_i[rr] - mn);
                m_i[rr] = mn;
#pragma unroll
                for (int nt = 0; nt < 16; ++nt) o[nt][rr] *= alpha;
                o_l[rr] *= alpha;
            }
        }
#pragma unroll
        for (int rr = 0; rr < 4; ++rr) {
            s0[rr] = __expf(s0[rr] - m_i[rr]);   // bounded by e^8
            s1[rr] = __expf(s1[rr] - m_i[rr]);
        }

        // --- P: C-layout -> A-layout via slot reuse (self-ordered in-wave) ---
        f16* pb = (f16*)slotr;                      // 16 rows x 40 f16 view
#pragma unroll
        for (int rr = 0; rr < 4; ++rr) {
            pb[(qd*4 + rr)*40 + mrow]      = (f16)s0[rr];
            pb[(qd*4 + rr)*40 + 16 + mrow] = (f16)s1[rr];
        }
        f16x8 pf = *(const f16x8*)&pb[mrow*40 + qd*8];
        o_l = __builtin_amdgcn_mfma_f32_16x16x32_f16(pf, ones, o_l, 0,0,0);

        // --- O_half += P @ V_half : 16 d-tiles ---
        {
            const f16* vb = &vbuf[j & 1][0];
            __builtin_amdgcn_s_setprio(1);
#pragma unroll
            for (int nt = 0; nt < 16; ++nt) {
                int dl = nt*16 + mrow;              // d = h*256 + dl
                f16x8 vf = *(const f16x8*)&vb[(cbase + dl*4 + ((qd + (dl >> 1)) & 3)) << 3];
                o[nt] = __builtin_amdgcn_mfma_f32_16x16x32_f16(pf, vf, o[nt], 0,0,0);
            }
            __builtin_amdgcn_s_setprio(0);
        }

        // --- partial S_{j+1} from kbuf[(j+1)&1] ---
        if (j < 127) {
            const f16* kb = &kbuf[(j + 1) & 1][0];
            f32x4 a0 = (f32x4){0.f,0.f,0.f,0.f}, a1 = a0;
            __builtin_amdgcn_s_setprio(1);
#pragma unroll
            for (int ksl = 0; ksl < 8; ++ksl) {
                f16x8 kf0 = *(const f16x8*)&kb[(cbase + n0a*32 + ((ksl*4 + qd + n0a) & 31)) << 3];
                f16x8 kf1 = *(const f16x8*)&kb[(cbase + n1a*32 + ((ksl*4 + qd + n1a) & 31)) << 3];
                a0 = __builtin_amdgcn_mfma_f32_16x16x32_f16(qf[ksl], kf0, a0, 0,0,0);
                a1 = __builtin_amdgcn_mfma_f32_16x16x32_f16(qf[ksl], kf1, a1, 0,0,0);
            }
            __builtin_amdgcn_s_setprio(0);
            s0p = a0; s1p = a1;
            f32x4* slotw = (f32x4*)&xch[(j + 1) & 1][qg][h][0];
            slotw[lane]      = s0p;
            slotw[64 + lane] = s1p;
        }

        __syncthreads();   // sole barrier: xch visible + DMA drained (full cover)
    }

    // epilogue: each wave owns rows [qg*16,+16) x cols [h*256,+256) fully
#pragma unroll
    for (int rr = 0; rr < 4; ++rr) {
        float inv_l = 1.f / o_l[rr];
        size_t grow = ((size_t)b*SEQ + qt*64 + qg*16 + qd*4 + rr) * DIM + h*256;
#pragma unroll
        for (int nt = 0; nt < 16; ++nt) {
            int col = nt*16 + mrow;
            float val = o[nt][rr] * inv_l + (float)qvh[grow + col];
            ao[grow + col] = (f16)val;
        }
    }
}

// ---------------------------------------------------------------------------
// Final linear: out[m,n] = sum_k ao[m,k]*Wf[n,k] + bf[n]  (f32 out)
// ---------------------------------------------------------------------------
__global__ __launch_bounds__(256) void final_gemm(
    const f16* __restrict__ ao, const float* __restrict__ Wf,
    const float* __restrict__ bf, float* __restrict__ out)
{
    __shared__ __attribute__((aligned(16))) f16 a_lds[128][40];
    __shared__ __attribute__((aligned(16))) f16 b_lds[128][40];

    const int m0 = blockIdx.y * 128, n0 = blockIdx.x * 128;
    const int tid = threadIdx.x, lane = tid & 63, wv = tid >> 6;
    const int wm = wv >> 1, wn = wv & 1, mrow = lane & 15, qd = lane >> 4;

    f32x4 acc[4][4];
#pragma unroll
    for (int mt = 0; mt < 4; ++mt)
#pragma unroll
        for (int nt = 0; nt < 4; ++nt) acc[mt][nt] = (f32x4){0.f,0.f,0.f,0.f};

    float bv[4];
#pragma unroll
    for (int nt = 0; nt < 4; ++nt) bv[nt] = bf[n0 + wn*64 + nt*16 + mrow];

    for (int k0 = 0; k0 < DIM; k0 += 32) {
        __syncthreads();
#pragma unroll
        for (int i = 0; i < 2; ++i) {
            int c = i*256 + tid;
            int row = c >> 2, c8 = c & 3;
            *(f16x8*)&a_lds[row][c8*8] =
                *(const f16x8*)(ao + (size_t)(m0+row)*DIM + k0 + c8*8);
        }
#pragma unroll
        for (int i = 0; i < 4; ++i) {
            int c = i*256 + tid;
            int row = c >> 3, c4 = c & 7;
            float4 v = *(const float4*)(Wf + (size_t)(n0+row)*DIM + k0 + c4*4);
            f16x4 hh = { (f16)v.x, (f16)v.y, (f16)v.z, (f16)v.w };
            *(f16x4*)&b_lds[row][c4*4] = hh;
        }
        __syncthreads();
        f16x8 af[4], bfr[4];
#pragma unroll
        for (int mt = 0; mt < 4; ++mt) af[mt]  = *(const f16x8*)&a_lds[wm*64 + mt*16 + mrow][qd*8];
#pragma unroll
        for (int nt = 0; nt < 4; ++nt) bfr[nt] = *(const f16x8*)&b_lds[wn*64 + nt*16 + mrow][qd*8];
#pragma unroll
        for (int mt = 0; mt < 4; ++mt)
#pragma unroll
            for (int nt = 0; nt < 4; ++nt)
                acc[mt][nt] = __builtin_amdgcn_mfma_f32_16x16x32_f16(af[mt], bfr[nt], acc[mt][nt], 0,0,0);
    }
#pragma unroll
    for (int mt = 0; mt < 4; ++mt)
#pragma unroll
        for (int r = 0; r < 4; ++r) {
            size_t grow = (size_t)(m0 + wm*64 + mt*16 + qd*4 + r) * DIM;
#pragma unroll
            for (int nt = 0; nt < 4; ++nt) {
                int col = n0 + wn*64 + nt*16 + mrow;
                out[grow + col] = acc[mt][nt][r] + bv[nt];
            }
        }
}

// ---------------------------------------------------------------------------
extern "C" void kernel_launch(void* const* d_in, const int* in_sizes, int n_in,
                              void* d_out, int out_size, void* d_ws, size_t ws_size,
                              hipStream_t stream)
{
    const float* x   = (const float*)d_in[0];
    const float* y   = (const float*)d_in[1];
    const float* Wq  = (const float*)d_in[2];
    const float* bq  = (const float*)d_in[3];
    const float* Wqv = (const float*)d_in[4];
    const float* bqv = (const float*)d_in[5];
    const float* Wk  = (const float*)d_in[6];
    const float* bk  = (const float*)d_in[7];
    const float* Wkv = (const float*)d_in[8];
    const float* bkv = (const float*)d_in[9];
    const float* Wf  = (const float*)d_in[10];
    const float* bf  = (const float*)d_in[11];
    float* out = (float*)d_out;

    f16* qh  = (f16*)d_ws;       // NEL f16 each; 80 MB total
    f16* qvh = qh  + NEL;
    f16* kS  = qvh + NEL;
    f16* vS  = kS  + NEL;
    f16* aob = vS  + NEL;

    proj_gemm<<<dim3(4, 128, 4), 256, 0, stream>>>(
        x, y, Wq, bq, Wqv, bqv, Wk, bk, Wkv, bkv, qh, qvh, kS, vS);
    attn_kernel<<<dim3(256), 512, 0, stream>>>(qh, kS, vS, qvh, aob);
    final_gemm<<<dim3(4, 128), 256, 0, stream>>>(aob, Wf, bf, out);
}